// Round 3
// baseline (247.538 us; speedup 1.0000x reference)
//
#include <hip/hip_runtime.h>
#include <math.h>

// GaussianAdjacencyMatrix: out[b,i,j] = m*exp(-||x_i-x_j||^2/sigma^2) / (row_sum + 1e-8)
// B=8, N=2048, D=3.
//
// Structure: one wave per row-group, 4 rows per wave, software-pipelined.
//  - Coords staged SoA in LDS once per block (16 rows amortize it). Coord reads
//    are ds_read_b128 (lgkmcnt) -> they do NOT serialize behind HBM mask loads
//    in the in-order vmcnt stream (this was the round-2 bottleneck: L1-hit coord
//    loads could not retire before older in-flight HBM mask loads).
//  - Masks are the only vmem loads. Two static register buffers A/B, fully
//    unrolled rotation: row r+1's 8 mask loads fly while row r computes.
//    Only the first row per wave pays exposed HBM latency.
//  - No runtime-indexed arrays (everything unrolled w/ constant indices).
//  - Nontemporal stores (out has zero reuse; keep L3 for masks).

#define NN      2048
#define THREADS 256
#define RPW     4                 // rows per wave
#define ROWS_PER_BLOCK 16         // 4 waves * RPW
#define EPS     1e-8f

typedef float vf4 __attribute__((ext_vector_type(4)));

__global__ __launch_bounds__(THREADS, 4) void gauss_adj_kernel(
    const float* __restrict__ coords,   // [B, N, 3]
    const float* __restrict__ masks,    // [B, N, N]
    const float* __restrict__ sigma,    // [1]
    float* __restrict__ out)            // [B, N, N]
{
    const int tid  = threadIdx.x;
    const int wid  = tid >> 6;
    const int lane = tid & 63;
    const int rowBase = blockIdx.x * ROWS_PER_BLOCK;   // 16 rows, same batch
    const int b = rowBase >> 11;                       // / 2048

    __shared__ __align__(16) float sx[NN];
    __shared__ __align__(16) float sy[NN];
    __shared__ __align__(16) float sz[NN];

    const float* cb = coords + (size_t)b * NN * 3;
    for (int idx = tid; idx < NN; idx += THREADS) {
        sx[idx] = cb[idx * 3 + 0];
        sy[idx] = cb[idx * 3 + 1];
        sz[idx] = cb[idx * 3 + 2];
    }
    __syncthreads();

    const float s = sigma[0];
    const float cexp = -1.44269504088896341f / (s * s);   // -log2(e)/sigma^2

    const int r0 = rowBase + wid * RPW;   // this wave's 4 consecutive rows
    const vf4* sx4 = (const vf4*)sx;
    const vf4* sy4 = (const vf4*)sy;
    const vf4* sz4 = (const vf4*)sz;

    vf4 A[8], B[8];   // only constant-indexed (unrolled) -> registers

#define LOADM(BUF, R) { \
    const vf4* mrow_ = (const vf4*)(masks + (size_t)(r0 + (R)) * NN); \
    _Pragma("unroll") \
    for (int w = 0; w < 8; ++w) BUF[w] = mrow_[w * 64 + lane]; }

#define PROC(BUF, R) { \
    const int i_ = (r0 + (R)) & (NN - 1); \
    const float xi = sx[i_], yi = sy[i_], zi = sz[i_]; \
    float lsum = 0.0f; \
    _Pragma("unroll") \
    for (int w = 0; w < 8; ++w) { \
        const int q_ = w * 64 + lane; \
        const vf4 X = sx4[q_], Y = sy4[q_], Z = sz4[q_]; \
        vf4 v = BUF[w]; \
        float dx, dy, dz, d; \
        dx = xi - X.x; dy = yi - Y.x; dz = zi - Z.x; d = dx*dx + dy*dy + dz*dz; \
        v.x *= exp2f(d * cexp); \
        dx = xi - X.y; dy = yi - Y.y; dz = zi - Z.y; d = dx*dx + dy*dy + dz*dz; \
        v.y *= exp2f(d * cexp); \
        dx = xi - X.z; dy = yi - Y.z; dz = zi - Z.z; d = dx*dx + dy*dy + dz*dz; \
        v.z *= exp2f(d * cexp); \
        dx = xi - X.w; dy = yi - Y.w; dz = zi - Z.w; d = dx*dx + dy*dy + dz*dz; \
        v.w *= exp2f(d * cexp); \
        BUF[w] = v; \
        lsum += (v.x + v.y) + (v.z + v.w); \
    } \
    _Pragma("unroll") \
    for (int off = 32; off > 0; off >>= 1) lsum += __shfl_xor(lsum, off, 64); \
    const float inv_ = 1.0f / (lsum + EPS); \
    vf4* orow_ = (vf4*)(out + (size_t)(r0 + (R)) * NN); \
    _Pragma("unroll") \
    for (int w = 0; w < 8; ++w) { \
        vf4 o = BUF[w]; \
        o.x *= inv_; o.y *= inv_; o.z *= inv_; o.w *= inv_; \
        __builtin_nontemporal_store(o, &orow_[w * 64 + lane]); \
    } }

    // depth-1 software pipeline over the wave's 4 rows (static A/B rotation)
    LOADM(A, 0)
    LOADM(B, 1)
    PROC(A, 0)
    LOADM(A, 2)
    PROC(B, 1)
    LOADM(B, 3)
    PROC(A, 2)
    PROC(B, 3)

#undef LOADM
#undef PROC
}

extern "C" void kernel_launch(void* const* d_in, const int* in_sizes, int n_in,
                              void* d_out, int out_size, void* d_ws, size_t ws_size,
                              hipStream_t stream) {
    const float* coords = (const float*)d_in[0];   // [B,N,3]
    const float* masks  = (const float*)d_in[1];   // [B,N,N]
    const float* sigma  = (const float*)d_in[2];   // [1]
    float* out = (float*)d_out;

    const int B    = in_sizes[0] / (NN * 3);
    const int rows = B * NN;
    gauss_adj_kernel<<<rows / ROWS_PER_BLOCK, THREADS, 0, stream>>>(coords, masks, sigma, out);
}

// Round 4
// 238.868 us; speedup vs baseline: 1.0363x; 1.0363x over previous
//
#include <hip/hip_runtime.h>
#include <math.h>

// GaussianAdjacencyMatrix: out[b,i,j] = m*exp(-||x_i-x_j||^2/sigma^2) / (row_sum + 1e-8)
// B=8, N=2048, D=3.
//
// v4: max-occupancy latency attack.
//  - Row-softmax is invariant to the row-constant factor exp(-||xi||^2/s^2), so
//    use A'[i,j] = exp2( xi*qx[j] + yi*qy[j] + zi*qz[j] + qw[j] ) with
//    q[j] = { 2x C, 2y C, 2z C, -||x||^2 C }, C = log2(e)/sigma^2.
//    -> 3 fma + 1 v_exp + 1 mul per element (was ~11 VALU ops).
//  - q planes staged SoA in LDS (32 KiB) -> coord reads are conflict-free
//    ds_read_b128 on the lgkm queue; ONLY mask loads occupy the in-order vmcnt
//    queue (R2's L1-behind-HBM retirement stall is gone), both issued up front.
//  - 512-thread block = 2 rows; 32 KiB LDS -> 4 blocks/CU -> 32 waves/CU (100%)
//    occupancy; __launch_bounds__(512,8) caps VGPR at 64 (est. ~50 live).
//  - Per-wave row chain: 2 mask loads + 8 ds_read_b128 + ~50 VALU + butterfly.

#define NN      2048
#define THREADS 512
#define EPS     1e-8f

typedef float vf4 __attribute__((ext_vector_type(4)));

__global__ __launch_bounds__(THREADS, 8) void gauss_adj_kernel(
    const float* __restrict__ coords,   // [B, N, 3]
    const float* __restrict__ masks,    // [B, N, N]
    const float* __restrict__ sigma,    // [1]
    float* __restrict__ out)            // [B, N, N]
{
    const int tid = threadIdx.x;
    const int rib = tid >> 8;            // row-in-block: 0 (waves 0-3), 1 (waves 4-7)
    const int tir = tid & 255;           // thread-in-row: 0..255
    const int row = blockIdx.x * 2 + rib;      // b*N + i
    const int b   = row >> 11;
    const int i   = row & (NN - 1);

    __shared__ __align__(16) float qx[NN];
    __shared__ __align__(16) float qy[NN];
    __shared__ __align__(16) float qz[NN];
    __shared__ __align__(16) float qw[NN];
    __shared__ float red[8];

    const float s = sigma[0];
    const float C = 1.44269504088896341f / (s * s);   // log2(e)/sigma^2
    const float* cb = coords + (size_t)b * NN * 3;

    for (int idx = tid; idx < NN; idx += THREADS) {
        const float x = cb[idx * 3 + 0];
        const float y = cb[idx * 3 + 1];
        const float z = cb[idx * 3 + 2];
        qx[idx] = 2.0f * C * x;
        qy[idx] = 2.0f * C * y;
        qz[idx] = 2.0f * C * z;
        qw[idx] = -C * (x * x + y * y + z * z);
    }
    __syncthreads();

    const float xi = cb[i * 3 + 0];
    const float yi = cb[i * 3 + 1];
    const float zi = cb[i * 3 + 2];

    const vf4* mrow = (const vf4*)(masks + (size_t)row * NN);
    vf4*       orow = (vf4*)(out + (size_t)row * NN);
    const vf4* qx4 = (const vf4*)qx;
    const vf4* qy4 = (const vf4*)qy;
    const vf4* qz4 = (const vf4*)qz;
    const vf4* qw4 = (const vf4*)qw;

    // both mask loads in flight before any compute (counted vmcnt waits)
    vf4 m0 = mrow[tir];
    vf4 m1 = mrow[256 + tir];

    float lsum = 0.0f;

#define DOCHUNK(M, Q) { \
        const int q_ = (Q); \
        const vf4 X = qx4[q_], Y = qy4[q_], Z = qz4[q_], W = qw4[q_]; \
        M.x *= exp2f(fmaf(xi, X.x, fmaf(yi, Y.x, fmaf(zi, Z.x, W.x)))); \
        M.y *= exp2f(fmaf(xi, X.y, fmaf(yi, Y.y, fmaf(zi, Z.y, W.y)))); \
        M.z *= exp2f(fmaf(xi, X.z, fmaf(yi, Y.z, fmaf(zi, Z.z, W.z)))); \
        M.w *= exp2f(fmaf(xi, X.w, fmaf(yi, Y.w, fmaf(zi, Z.w, W.w)))); \
        lsum += (M.x + M.y) + (M.z + M.w); \
    }

    DOCHUNK(m0, tir)
    DOCHUNK(m1, 256 + tir)
#undef DOCHUNK

    // wave butterfly, then cross-wave combine for this row (4 waves/row)
    #pragma unroll
    for (int off = 32; off > 0; off >>= 1)
        lsum += __shfl_xor(lsum, off, 64);
    if ((tid & 63) == 0) red[tid >> 6] = lsum;
    __syncthreads();
    const int rb = rib * 4;
    const float tot = (red[rb] + red[rb + 1]) + (red[rb + 2] + red[rb + 3]);
    const float inv = 1.0f / (tot + EPS);

    m0.x *= inv; m0.y *= inv; m0.z *= inv; m0.w *= inv;
    m1.x *= inv; m1.y *= inv; m1.z *= inv; m1.w *= inv;
    __builtin_nontemporal_store(m0, &orow[tir]);
    __builtin_nontemporal_store(m1, &orow[256 + tir]);
}

extern "C" void kernel_launch(void* const* d_in, const int* in_sizes, int n_in,
                              void* d_out, int out_size, void* d_ws, size_t ws_size,
                              hipStream_t stream) {
    const float* coords = (const float*)d_in[0];   // [B,N,3]
    const float* masks  = (const float*)d_in[1];   // [B,N,N]
    const float* sigma  = (const float*)d_in[2];   // [1]
    float* out = (float*)d_out;

    const int B    = in_sizes[0] / (NN * 3);
    const int rows = B * NN;
    gauss_adj_kernel<<<rows / 2, THREADS, 0, stream>>>(coords, masks, sigma, out);
}